// Round 9
// baseline (658.088 us; speedup 1.0000x reference)
//
#include <hip/hip_runtime.h>
#include <cstdint>

typedef unsigned short u16;
typedef unsigned int u32;
typedef __attribute__((ext_vector_type(8))) short short8;   // 8 bf16 (MFMA A/B frag)
typedef __attribute__((ext_vector_type(4))) float floatx4;  // MFMA C/D frag
typedef __attribute__((ext_vector_type(2))) float f32x2;

__device__ __forceinline__ float b2f(u16 u) {
    union { unsigned int i; float f; } c; c.i = ((unsigned int)u) << 16; return c.f;
}
__device__ __forceinline__ u16 f2b(float f) {
    union { float f; unsigned int i; } c; c.f = f;
    unsigned int u = c.i;
    u = u + 0x7FFFu + ((u >> 16) & 1u);   // RNE
    return (u16)(u >> 16);
}
__device__ __forceinline__ float rdlane(float v, int l) {
    union { float f; int i; } c; c.f = v;
    union { int i; float f; } o; o.i = __builtin_amdgcn_readlane(c.i, l);
    return o.f;
}
__device__ __forceinline__ u32 f2u(float f) { union { float f; u32 u; } c; c.f = f; return c.u; }
__device__ __forceinline__ float u2f(u32 u) { union { u32 u; float f; } c; c.u = u; return c.f; }
__device__ __forceinline__ f32x2 vfma2(f32x2 a, f32x2 b, f32x2 c) {
    f32x2 r;
    r.x = __builtin_fmaf(a.x, b.x, c.x);
    r.y = __builtin_fmaf(a.y, b.y, c.y);
    return r;
}

// ---------------------------------------------------------------------------
// Fused Q/K/V projection GEMM. Y[m,n] = sum_k x[m,k]*W[n,k] + bias[n].
// grid (32, 24): which = blockIdx.y>>3 (0=q fp32, 1=k bf16, 2=v fp32).
// ---------------------------------------------------------------------------
__global__ __launch_bounds__(256) void gemm_qkv(
    const float* __restrict__ x,
    const float* __restrict__ Wq, const float* __restrict__ Wk, const float* __restrict__ Wv,
    const float* __restrict__ bq, const float* __restrict__ bk, const float* __restrict__ bv,
    float* __restrict__ qout, u16* __restrict__ kout, float* __restrict__ vout)
{
    __shared__ u16 xs[64 * 72];
    __shared__ u16 wsl[64 * 72];
    int tid = threadIdx.x;
    int lane = tid & 63;
    int wv = tid >> 6;
    int lo = lane & 15, hi = lane >> 4;
    int which = blockIdx.y >> 3;
    int m0 = blockIdx.x * 64, n0 = (blockIdx.y & 7) * 64;
    const float* W    = which == 0 ? Wq : (which == 1 ? Wk : Wv);
    const float* bias = which == 0 ? bq : (which == 1 ? bk : bv);

    floatx4 acc[4];
#pragma unroll
    for (int mt = 0; mt < 4; ++mt) acc[mt] = (floatx4){0.f, 0.f, 0.f, 0.f};

    for (int k0 = 0; k0 < 512; k0 += 64) {
        __syncthreads();
#pragma unroll
        for (int i = 0; i < 2; ++i) {
            int v = tid + i * 256;
            int row = v >> 3, c8 = (v & 7) * 8;
            const float* ap = x + (m0 + row) * 512 + k0 + c8;
            const float* wp = W + (n0 + row) * 512 + k0 + c8;
            float4 a0 = *(const float4*)(ap);
            float4 a1 = *(const float4*)(ap + 4);
            float4 w0 = *(const float4*)(wp);
            float4 w1v = *(const float4*)(wp + 4);
            union { u16 u[8]; uint4 q; } ca, cw;
            ca.u[0] = f2b(a0.x); ca.u[1] = f2b(a0.y); ca.u[2] = f2b(a0.z); ca.u[3] = f2b(a0.w);
            ca.u[4] = f2b(a1.x); ca.u[5] = f2b(a1.y); ca.u[6] = f2b(a1.z); ca.u[7] = f2b(a1.w);
            cw.u[0] = f2b(w0.x); cw.u[1] = f2b(w0.y); cw.u[2] = f2b(w0.z); cw.u[3] = f2b(w0.w);
            cw.u[4] = f2b(w1v.x); cw.u[5] = f2b(w1v.y); cw.u[6] = f2b(w1v.z); cw.u[7] = f2b(w1v.w);
            *(uint4*)(xs + row * 72 + c8)  = ca.q;
            *(uint4*)(wsl + row * 72 + c8) = cw.q;
        }
        __syncthreads();
#pragma unroll
        for (int ks = 0; ks < 2; ++ks) {
            short8 bfr = *(const short8*)(wsl + (wv * 16 + lo) * 72 + ks * 32 + hi * 8);
#pragma unroll
            for (int mt = 0; mt < 4; ++mt) {
                short8 afr = *(const short8*)(xs + (mt * 16 + lo) * 72 + ks * 32 + hi * 8);
                acc[mt] = __builtin_amdgcn_mfma_f32_16x16x32_bf16(afr, bfr, acc[mt], 0, 0, 0);
            }
        }
    }

    int n = n0 + wv * 16 + lo;
    float bv2 = bias[n];
    int h = n >> 6, dd = n & 63;
#pragma unroll
    for (int mt = 0; mt < 4; ++mt) {
#pragma unroll
        for (int r = 0; r < 4; ++r) {
            int m = m0 + mt * 16 + hi * 4 + r;      // C/D: row=(lane>>4)*4+reg, col=lane&15
            float y = acc[mt][r] + bv2;
            int b = m >> 10, c = m & 1023;
            int idx = (((b * 8 + h) * 1024) + c) * 64 + dd;
            if (which == 0)      qout[idx] = y;
            else if (which == 1) kout[idx] = f2b(y);
            else                 vout[idx] = y;
        }
    }
}

// ---------------------------------------------------------------------------
// Output GEMM: Y[m,n] = sum_k A[m,k]*Wo[n,k] + bo[n], fp32 out, [m*512+n].
// ---------------------------------------------------------------------------
__global__ __launch_bounds__(256) void gemm_out(
    const float* __restrict__ A, const float* __restrict__ W, const float* __restrict__ bias,
    float* __restrict__ outf)
{
    __shared__ u16 xs[64 * 72];
    __shared__ u16 wsl[64 * 72];
    int tid = threadIdx.x;
    int lane = tid & 63;
    int wv = tid >> 6;
    int lo = lane & 15, hi = lane >> 4;
    int m0 = blockIdx.x * 64, n0 = blockIdx.y * 64;

    floatx4 acc[4];
#pragma unroll
    for (int mt = 0; mt < 4; ++mt) acc[mt] = (floatx4){0.f, 0.f, 0.f, 0.f};

    for (int k0 = 0; k0 < 512; k0 += 64) {
        __syncthreads();
#pragma unroll
        for (int i = 0; i < 2; ++i) {
            int v = tid + i * 256;
            int row = v >> 3, c8 = (v & 7) * 8;
            const float* ap = A + (m0 + row) * 512 + k0 + c8;
            const float* wp = W + (n0 + row) * 512 + k0 + c8;
            float4 a0 = *(const float4*)(ap);
            float4 a1 = *(const float4*)(ap + 4);
            float4 w0 = *(const float4*)(wp);
            float4 w1v = *(const float4*)(wp + 4);
            union { u16 u[8]; uint4 q; } ca, cw;
            ca.u[0] = f2b(a0.x); ca.u[1] = f2b(a0.y); ca.u[2] = f2b(a0.z); ca.u[3] = f2b(a0.w);
            ca.u[4] = f2b(a1.x); ca.u[5] = f2b(a1.y); ca.u[6] = f2b(a1.z); ca.u[7] = f2b(a1.w);
            cw.u[0] = f2b(w0.x); cw.u[1] = f2b(w0.y); cw.u[2] = f2b(w0.z); cw.u[3] = f2b(w0.w);
            cw.u[4] = f2b(w1v.x); cw.u[5] = f2b(w1v.y); cw.u[6] = f2b(w1v.z); cw.u[7] = f2b(w1v.w);
            *(uint4*)(xs + row * 72 + c8)  = ca.q;
            *(uint4*)(wsl + row * 72 + c8) = cw.q;
        }
        __syncthreads();
#pragma unroll
        for (int ks = 0; ks < 2; ++ks) {
            short8 bfr = *(const short8*)(wsl + (wv * 16 + lo) * 72 + ks * 32 + hi * 8);
#pragma unroll
            for (int mt = 0; mt < 4; ++mt) {
                short8 afr = *(const short8*)(xs + (mt * 16 + lo) * 72 + ks * 32 + hi * 8);
                acc[mt] = __builtin_amdgcn_mfma_f32_16x16x32_bf16(afr, bfr, acc[mt], 0, 0, 0);
            }
        }
    }

    int n = n0 + wv * 16 + lo;
    float bv = bias[n];
#pragma unroll
    for (int mt = 0; mt < 4; ++mt)
#pragma unroll
        for (int r = 0; r < 4; ++r) {
            int m = m0 + mt * 16 + hi * 4 + r;
            outf[m * 512 + n] = acc[mt][r] + bv;
        }
}

// ---------------------------------------------------------------------------
// Fused second-order attention, v5. Changes vs v4:
//  * trans-free sigmoid: 2^z via RNE magic-constant split (n from bits of
//    z+1.5*2^23, scale = bitcast((bits<<23)+0x3F800000), deg-3 poly for 2^f
//    on [-0.5,0.5], rel err <= 6.5e-4 -> delta-sigma <= 1.6e-4).
//  * pair-merged reciprocal: 1/a0 and 1/a1 from one v_rcp(a0*a1).
//    Per eval-pair: 4 trans + 10 VALU -> 1 trans + ~26 VALU.
//  * qp+b1 back in the MFMA C-init (off the gelu critical path).
// ---------------------------------------------------------------------------
__global__ __launch_bounds__(256, 3) void attn5(
    const float* __restrict__ qf, const u16* __restrict__ kb, const float* __restrict__ vf,
    const float* __restrict__ w1, const float* __restrict__ b1, const float* __restrict__ w2,
    float* __restrict__ ao)
{
    __shared__ float q_l[4 * 64];
    int tid = threadIdx.x;
    int lane = tid & 63;
    int wv = tid >> 6;
    int lo = lane & 15, hi = lane >> 4;
    int bh = blockIdx.x >> 8;                      // 0..15 = b*8+h
    int qi = ((blockIdx.x & 255) << 2) | wv;       // query 0..1023

    q_l[wv * 64 + lane] = qf[(bh * 1024 + qi) * 64 + lane];

    // qp[e]+b1[e] at lane=e
    float qpacc = b1[lane];
#pragma unroll
    for (int d8 = 0; d8 < 64; d8 += 8) {
        float4 wa = *(const float4*)(w1 + lane * 192 + d8);
        float4 wb = *(const float4*)(w1 + lane * 192 + d8 + 4);
        const float* q8 = q_l + wv * 64 + d8;      // wave-uniform broadcast reads
        qpacc = __builtin_fmaf(q8[0], wa.x, qpacc);
        qpacc = __builtin_fmaf(q8[1], wa.y, qpacc);
        qpacc = __builtin_fmaf(q8[2], wa.z, qpacc);
        qpacc = __builtin_fmaf(q8[3], wa.w, qpacc);
        qpacc = __builtin_fmaf(q8[4], wb.x, qpacc);
        qpacc = __builtin_fmaf(q8[5], wb.y, qpacc);
        qpacc = __builtin_fmaf(q8[6], wb.z, qpacc);
        qpacc = __builtin_fmaf(q8[7], wb.w, qpacc);
    }
    // rearrange to C/D-row indexing: e = mt*16 + hi*4 + r
    float qpb[4][4], w2c[4][4];
    float w2row = w2[lane] * 0.18033688f;          // w2[e] * (1/8) * log2(e)
#pragma unroll
    for (int mt = 0; mt < 4; ++mt)
#pragma unroll
        for (int r = 0; r < 4; ++r) {
            int e = mt * 16 + hi * 4 + r;
            qpb[mt][r] = __shfl(qpacc, e);
            w2c[mt][r] = __shfl(w2row, e);
        }

    // q pieces for frag build: qv2[ks][j] = q[ks*32 + hi*8 + j]
    float qv2[2][8];
#pragma unroll
    for (int ks = 0; ks < 2; ++ks)
#pragma unroll
        for (int j = 0; j < 8; ++j)
            qv2[ks][j] = q_l[wv * 64 + ks * 32 + hi * 8 + j];

    // A-frags: qw'[e = mt*16+lo][dd = ks*32 + hi*8 + j], bf16
    short8 af[4][2];
#pragma unroll
    for (int mt = 0; mt < 4; ++mt) {
        const float* wr = w1 + (mt * 16 + lo) * 192;
#pragma unroll
        for (int ks = 0; ks < 2; ++ks) {
            int dd0 = ks * 32 + hi * 8;
            float4 a0 = *(const float4*)(wr + 128 + dd0);
            float4 a1 = *(const float4*)(wr + 128 + dd0 + 4);
            float4 k0 = *(const float4*)(wr + 64 + dd0);
            float4 k1 = *(const float4*)(wr + 64 + dd0 + 4);
            union { u16 u[8]; short8 s; } cv;
            cv.u[0] = f2b(__builtin_fmaf(qv2[ks][0], a0.x, k0.x));
            cv.u[1] = f2b(__builtin_fmaf(qv2[ks][1], a0.y, k0.y));
            cv.u[2] = f2b(__builtin_fmaf(qv2[ks][2], a0.z, k0.z));
            cv.u[3] = f2b(__builtin_fmaf(qv2[ks][3], a0.w, k0.w));
            cv.u[4] = f2b(__builtin_fmaf(qv2[ks][4], a1.x, k1.x));
            cv.u[5] = f2b(__builtin_fmaf(qv2[ks][5], a1.y, k1.y));
            cv.u[6] = f2b(__builtin_fmaf(qv2[ks][6], a1.z, k1.z));
            cv.u[7] = f2b(__builtin_fmaf(qv2[ks][7], a1.w, k1.w));
            af[mt][ks] = cv.s;
        }
    }

    float l_run = 0.f;
    float oa0 = 0.f, oa1 = 0.f, oa2 = 0.f, oa3 = 0.f;
    const u16*   kbase = kb + bh * 65536;
    const float* vbase = vf + bh * 65536;

    const float NA = -2.45546696f;                 // -1.702 * log2(e)
    const float MC = 12582912.0f;                  // 1.5 * 2^23 (RNE magic)

    for (int j0 = 0; j0 < 1024; j0 += 32) {
        // B-frags direct from global: k[j = j0 + t*16 + lo][dd = ks*32 + hi*8]
        short8 bf[2][2];
#pragma unroll
        for (int t = 0; t < 2; ++t)
#pragma unroll
            for (int ks = 0; ks < 2; ++ks) {
                uint4 kv = *(const uint4*)(kbase + (j0 + t * 16 + lo) * 64 + ks * 32 + hi * 8);
                bf[t][ks] = *(short8*)&kv;
            }

        floatx4 acc[4][2];
#pragma unroll
        for (int mt = 0; mt < 4; ++mt)
#pragma unroll
            for (int t = 0; t < 2; ++t)
                acc[mt][t] = (floatx4){qpb[mt][0], qpb[mt][1], qpb[mt][2], qpb[mt][3]};
#pragma unroll
        for (int mt = 0; mt < 4; ++mt)
#pragma unroll
            for (int t = 0; t < 2; ++t)
                acc[mt][t] = __builtin_amdgcn_mfma_f32_16x16x32_bf16(af[mt][0], bf[t][0], acc[mt][t], 0, 0, 0);
#pragma unroll
        for (int mt = 0; mt < 4; ++mt)
#pragma unroll
            for (int t = 0; t < 2; ++t)
                acc[mt][t] = __builtin_amdgcn_mfma_f32_16x16x32_bf16(af[mt][1], bf[t][1], acc[mt][t], 0, 0, 0);

        // score[j]: sigmoid-gelu, trans-free sigma, merged rcp per pair
        f32x2 sacc = {0.f, 0.f};
#pragma unroll
        for (int mt = 0; mt < 4; ++mt)
#pragma unroll
            for (int r = 0; r < 4; ++r) {
                f32x2 x01 = {acc[mt][0][r], acc[mt][1][r]};
                f32x2 na2 = {NA, NA}, mc2 = {MC, MC};
                f32x2 t01 = vfma2(x01, na2, mc2);           // z + magic (RNE int in bits)
                f32x2 m01 = mc2 - t01;                      // -n (float)
                f32x2 f01 = vfma2(x01, na2, m01);           // f = z - n in [-0.5, 0.5]
                u32 sb0 = (f2u(t01.x) << 23) + 0x3F800000u; // 2^n bits
                u32 sb1 = (f2u(t01.y) << 23) + 0x3F800000u;
                f32x2 c3 = {0.0555041f, 0.0555041f}, c2v = {0.2402265f, 0.2402265f};
                f32x2 c1 = {0.6931472f, 0.6931472f}, one = {1.0f, 1.0f};
                f32x2 p01 = vfma2(f01, c3, c2v);
                p01 = vfma2(f01, p01, c1);
                p01 = vfma2(f01, p01, one);                 // 2^f
                f32x2 sc2 = {u2f(sb0), u2f(sb1)};
                f32x2 e01 = p01 * sc2;                      // e = 2^z
                f32x2 a01 = e01 + one;
                float rc = __builtin_amdgcn_rcpf(a01.x * a01.y);
                f32x2 rcv = {rc, rc};
                f32x2 asw = {a01.y, a01.x};
                f32x2 s01 = rcv * asw;                      // sigma pair
                f32x2 wc2 = {w2c[mt][r], w2c[mt][r]};
                f32x2 u01 = x01 * wc2;
                sacc = vfma2(u01, s01, sacc);
            }
        float s0 = sacc.x, s1 = sacc.y;
        s0 += __shfl_xor(s0, 16); s0 += __shfl_xor(s0, 32);   // s[j=lo]
        s1 += __shfl_xor(s1, 16); s1 += __shfl_xor(s1, 32);   // s[j=16+lo]

        // fixed-shift softmax numerator (scores bounded, safe)
        float p0 = __builtin_amdgcn_exp2f(s0 - 16.0f);
        float p1 = __builtin_amdgcn_exp2f(s1 - 16.0f);
        l_run += p0 + p1;                          // per-lane partial (over lo)

        // PV: p[j=lane&15] lives in p0/p1 -> v_readlane broadcast, SGPR fma
        const float* vrow = vbase + j0 * 64 + lane;
#pragma unroll
        for (int j = 0; j < 16; j += 4) {
            float pa0 = rdlane(p0, j + 0), pb0 = rdlane(p1, j + 0);
            float pa1 = rdlane(p0, j + 1), pb1 = rdlane(p1, j + 1);
            float pa2 = rdlane(p0, j + 2), pb2 = rdlane(p1, j + 2);
            float pa3 = rdlane(p0, j + 3), pb3 = rdlane(p1, j + 3);
            oa0 = __builtin_fmaf(pa0, vrow[(j + 0) * 64], oa0);
            oa1 = __builtin_fmaf(pa1, vrow[(j + 1) * 64], oa1);
            oa2 = __builtin_fmaf(pa2, vrow[(j + 2) * 64], oa2);
            oa3 = __builtin_fmaf(pa3, vrow[(j + 3) * 64], oa3);
            oa0 = __builtin_fmaf(pb0, vrow[(j + 16) * 64], oa0);
            oa1 = __builtin_fmaf(pb1, vrow[(j + 17) * 64], oa1);
            oa2 = __builtin_fmaf(pb2, vrow[(j + 18) * 64], oa2);
            oa3 = __builtin_fmaf(pb3, vrow[(j + 19) * 64], oa3);
        }
    }

    float l = l_run;
    l += __shfl_xor(l, 1); l += __shfl_xor(l, 2);
    l += __shfl_xor(l, 4); l += __shfl_xor(l, 8);
    float outv = (oa0 + oa1 + oa2 + oa3) * __builtin_amdgcn_rcpf(l);
    int b = bh >> 3, h = bh & 7;
    ao[(b * 1024 + qi) * 512 + h * 64 + lane] = outv;   // (B,C,D) fp32
}

// ---------------------------------------------------------------------------
extern "C" void kernel_launch(void* const* d_in, const int* in_sizes, int n_in,
                              void* d_out, int out_size, void* d_ws, size_t ws_size,
                              hipStream_t stream)
{
    (void)in_sizes; (void)n_in; (void)out_size; (void)ws_size;
    const float* x  = (const float*)d_in[0];
    const float* Wq = (const float*)d_in[1];
    const float* bq = (const float*)d_in[2];
    const float* Wk = (const float*)d_in[3];
    const float* bk = (const float*)d_in[4];
    const float* Wv = (const float*)d_in[5];
    const float* bv = (const float*)d_in[6];
    const float* w1 = (const float*)d_in[7];
    const float* b1 = (const float*)d_in[8];
    const float* w2 = (const float*)d_in[9];
    // d_in[10] = b2: scalar shift of all scores -> softmax-invariant -> unused
    const float* Wo = (const float*)d_in[11];
    const float* bo = (const float*)d_in[12];

    char* ws = (char*)d_ws;
    float* q_ws = (float*)(ws);               // 4 MB fp32 (b,h,c,d)
    u16*   k_ws = (u16*)(ws + (4u << 20));    // 2 MB bf16 (b,h,c,d)
    float* v_ws = (float*)(ws + (6u << 20));  // 4 MB fp32 (b,h,c,d)
    float* a_ws = (float*)(ws + (10u << 20)); // 4 MB fp32 (b,c,D)

    dim3 blk(256);
    hipLaunchKernelGGL(gemm_qkv, dim3(32, 24), blk, 0, stream,
                       x, Wq, Wk, Wv, bq, bk, bv, q_ws, k_ws, v_ws);
    hipLaunchKernelGGL(attn5, dim3(4096), blk, 0, stream, q_ws, k_ws, v_ws, w1, b1, w2, a_ws);
    hipLaunchKernelGGL(gemm_out, dim3(32, 8), blk, 0, stream, a_ws, Wo, bo, (float*)d_out);
}

// Round 10
// 569.522 us; speedup vs baseline: 1.1555x; 1.1555x over previous
//
#include <hip/hip_runtime.h>
#include <cstdint>

typedef unsigned short u16;
typedef __attribute__((ext_vector_type(8))) short short8;   // 8 bf16 (MFMA A/B frag)
typedef __attribute__((ext_vector_type(4))) float floatx4;  // MFMA C/D frag

__device__ __forceinline__ float b2f(u16 u) {
    union { unsigned int i; float f; } c; c.i = ((unsigned int)u) << 16; return c.f;
}
__device__ __forceinline__ u16 f2b(float f) {
    union { float f; unsigned int i; } c; c.f = f;
    unsigned int u = c.i;
    u = u + 0x7FFFu + ((u >> 16) & 1u);   // RNE
    return (u16)(u >> 16);
}
__device__ __forceinline__ float rdlane(float v, int l) {
    union { float f; int i; } c; c.f = v;
    union { int i; float f; } o; o.i = __builtin_amdgcn_readlane(c.i, l);
    return o.f;
}

// ---------------------------------------------------------------------------
// Fused Q/K/V projection GEMM. Y[m,n] = sum_k x[m,k]*W[n,k] + bias[n].
// grid (32, 24): which = blockIdx.y>>3 (0=q fp32, 1=k bf16, 2=v fp32).
// ---------------------------------------------------------------------------
__global__ __launch_bounds__(256) void gemm_qkv(
    const float* __restrict__ x,
    const float* __restrict__ Wq, const float* __restrict__ Wk, const float* __restrict__ Wv,
    const float* __restrict__ bq, const float* __restrict__ bk, const float* __restrict__ bv,
    float* __restrict__ qout, u16* __restrict__ kout, float* __restrict__ vout)
{
    __shared__ u16 xs[64 * 72];
    __shared__ u16 wsl[64 * 72];
    int tid = threadIdx.x;
    int lane = tid & 63;
    int wv = tid >> 6;
    int lo = lane & 15, hi = lane >> 4;
    int which = blockIdx.y >> 3;
    int m0 = blockIdx.x * 64, n0 = (blockIdx.y & 7) * 64;
    const float* W    = which == 0 ? Wq : (which == 1 ? Wk : Wv);
    const float* bias = which == 0 ? bq : (which == 1 ? bk : bv);

    floatx4 acc[4];
#pragma unroll
    for (int mt = 0; mt < 4; ++mt) acc[mt] = (floatx4){0.f, 0.f, 0.f, 0.f};

    for (int k0 = 0; k0 < 512; k0 += 64) {
        __syncthreads();
#pragma unroll
        for (int i = 0; i < 2; ++i) {
            int v = tid + i * 256;
            int row = v >> 3, c8 = (v & 7) * 8;
            const float* ap = x + (m0 + row) * 512 + k0 + c8;
            const float* wp = W + (n0 + row) * 512 + k0 + c8;
            float4 a0 = *(const float4*)(ap);
            float4 a1 = *(const float4*)(ap + 4);
            float4 w0 = *(const float4*)(wp);
            float4 w1v = *(const float4*)(wp + 4);
            union { u16 u[8]; uint4 q; } ca, cw;
            ca.u[0] = f2b(a0.x); ca.u[1] = f2b(a0.y); ca.u[2] = f2b(a0.z); ca.u[3] = f2b(a0.w);
            ca.u[4] = f2b(a1.x); ca.u[5] = f2b(a1.y); ca.u[6] = f2b(a1.z); ca.u[7] = f2b(a1.w);
            cw.u[0] = f2b(w0.x); cw.u[1] = f2b(w0.y); cw.u[2] = f2b(w0.z); cw.u[3] = f2b(w0.w);
            cw.u[4] = f2b(w1v.x); cw.u[5] = f2b(w1v.y); cw.u[6] = f2b(w1v.z); cw.u[7] = f2b(w1v.w);
            *(uint4*)(xs + row * 72 + c8)  = ca.q;
            *(uint4*)(wsl + row * 72 + c8) = cw.q;
        }
        __syncthreads();
#pragma unroll
        for (int ks = 0; ks < 2; ++ks) {
            short8 bfr = *(const short8*)(wsl + (wv * 16 + lo) * 72 + ks * 32 + hi * 8);
#pragma unroll
            for (int mt = 0; mt < 4; ++mt) {
                short8 afr = *(const short8*)(xs + (mt * 16 + lo) * 72 + ks * 32 + hi * 8);
                acc[mt] = __builtin_amdgcn_mfma_f32_16x16x32_bf16(afr, bfr, acc[mt], 0, 0, 0);
            }
        }
    }

    int n = n0 + wv * 16 + lo;
    float bv2 = bias[n];
    int h = n >> 6, dd = n & 63;
#pragma unroll
    for (int mt = 0; mt < 4; ++mt) {
#pragma unroll
        for (int r = 0; r < 4; ++r) {
            int m = m0 + mt * 16 + hi * 4 + r;      // C/D: row=(lane>>4)*4+reg, col=lane&15
            float y = acc[mt][r] + bv2;
            int b = m >> 10, c = m & 1023;
            int idx = (((b * 8 + h) * 1024) + c) * 64 + dd;
            if (which == 0)      qout[idx] = y;
            else if (which == 1) kout[idx] = f2b(y);
            else                 vout[idx] = y;
        }
    }
}

// ---------------------------------------------------------------------------
// Output GEMM: Y[m,n] = sum_k A[m,k]*Wo[n,k] + bo[n], fp32 out, [m*512+n].
// ---------------------------------------------------------------------------
__global__ __launch_bounds__(256) void gemm_out(
    const float* __restrict__ A, const float* __restrict__ W, const float* __restrict__ bias,
    float* __restrict__ outf)
{
    __shared__ u16 xs[64 * 72];
    __shared__ u16 wsl[64 * 72];
    int tid = threadIdx.x;
    int lane = tid & 63;
    int wv = tid >> 6;
    int lo = lane & 15, hi = lane >> 4;
    int m0 = blockIdx.x * 64, n0 = blockIdx.y * 64;

    floatx4 acc[4];
#pragma unroll
    for (int mt = 0; mt < 4; ++mt) acc[mt] = (floatx4){0.f, 0.f, 0.f, 0.f};

    for (int k0 = 0; k0 < 512; k0 += 64) {
        __syncthreads();
#pragma unroll
        for (int i = 0; i < 2; ++i) {
            int v = tid + i * 256;
            int row = v >> 3, c8 = (v & 7) * 8;
            const float* ap = A + (m0 + row) * 512 + k0 + c8;
            const float* wp = W + (n0 + row) * 512 + k0 + c8;
            float4 a0 = *(const float4*)(ap);
            float4 a1 = *(const float4*)(ap + 4);
            float4 w0 = *(const float4*)(wp);
            float4 w1v = *(const float4*)(wp + 4);
            union { u16 u[8]; uint4 q; } ca, cw;
            ca.u[0] = f2b(a0.x); ca.u[1] = f2b(a0.y); ca.u[2] = f2b(a0.z); ca.u[3] = f2b(a0.w);
            ca.u[4] = f2b(a1.x); ca.u[5] = f2b(a1.y); ca.u[6] = f2b(a1.z); ca.u[7] = f2b(a1.w);
            cw.u[0] = f2b(w0.x); cw.u[1] = f2b(w0.y); cw.u[2] = f2b(w0.z); cw.u[3] = f2b(w0.w);
            cw.u[4] = f2b(w1v.x); cw.u[5] = f2b(w1v.y); cw.u[6] = f2b(w1v.z); cw.u[7] = f2b(w1v.w);
            *(uint4*)(xs + row * 72 + c8)  = ca.q;
            *(uint4*)(wsl + row * 72 + c8) = cw.q;
        }
        __syncthreads();
#pragma unroll
        for (int ks = 0; ks < 2; ++ks) {
            short8 bfr = *(const short8*)(wsl + (wv * 16 + lo) * 72 + ks * 32 + hi * 8);
#pragma unroll
            for (int mt = 0; mt < 4; ++mt) {
                short8 afr = *(const short8*)(xs + (mt * 16 + lo) * 72 + ks * 32 + hi * 8);
                acc[mt] = __builtin_amdgcn_mfma_f32_16x16x32_bf16(afr, bfr, acc[mt], 0, 0, 0);
            }
        }
    }

    int n = n0 + wv * 16 + lo;
    float bv = bias[n];
#pragma unroll
    for (int mt = 0; mt < 4; ++mt)
#pragma unroll
        for (int r = 0; r < 4; ++r) {
            int m = m0 + mt * 16 + hi * 4 + r;
            outf[m * 512 + n] = acc[mt][r] + bv;
        }
}

// ---------------------------------------------------------------------------
// Fused second-order attention, v6 = v4 (best structure) + two edits:
//  * software-pipelined k prefetch: next iter's B-frags load at loop top,
//    consumed next iter -> ~200cy L2 latency overlapped with the iter body.
//  * pair-merged reciprocal in the HW-trans sigmoid: rc = rcp(a0*a1),
//    sigma0 = rc*a1, sigma1 = rc*a0 (3 trans + 11 VALU per pair, was 4+8).
//    Overflow (a0*a1 -> inf) only when both sigmas ~= 0; rc=0 = exact limit.
// ---------------------------------------------------------------------------
__global__ __launch_bounds__(256, 3) void attn6(
    const float* __restrict__ qf, const u16* __restrict__ kb, const float* __restrict__ vf,
    const float* __restrict__ w1, const float* __restrict__ b1, const float* __restrict__ w2,
    float* __restrict__ ao)
{
    __shared__ float q_l[4 * 64];
    int tid = threadIdx.x;
    int lane = tid & 63;
    int wv = tid >> 6;
    int lo = lane & 15, hi = lane >> 4;
    int bh = blockIdx.x >> 8;                      // 0..15 = b*8+h
    int qi = ((blockIdx.x & 255) << 2) | wv;       // query 0..1023

    q_l[wv * 64 + lane] = qf[(bh * 1024 + qi) * 64 + lane];

    // qp[e]+b1[e] at lane=e
    float qpacc = b1[lane];
#pragma unroll
    for (int d8 = 0; d8 < 64; d8 += 8) {
        float4 wa = *(const float4*)(w1 + lane * 192 + d8);
        float4 wb = *(const float4*)(w1 + lane * 192 + d8 + 4);
        const float* q8 = q_l + wv * 64 + d8;      // wave-uniform broadcast reads
        qpacc = __builtin_fmaf(q8[0], wa.x, qpacc);
        qpacc = __builtin_fmaf(q8[1], wa.y, qpacc);
        qpacc = __builtin_fmaf(q8[2], wa.z, qpacc);
        qpacc = __builtin_fmaf(q8[3], wa.w, qpacc);
        qpacc = __builtin_fmaf(q8[4], wb.x, qpacc);
        qpacc = __builtin_fmaf(q8[5], wb.y, qpacc);
        qpacc = __builtin_fmaf(q8[6], wb.z, qpacc);
        qpacc = __builtin_fmaf(q8[7], wb.w, qpacc);
    }
    // rearrange to C/D-row indexing: e = mt*16 + hi*4 + r
    float qpb[4][4], w2c[4][4];
    float w2row = w2[lane] * 0.18033688f;          // w2[e] * (1/8) * log2(e)
#pragma unroll
    for (int mt = 0; mt < 4; ++mt)
#pragma unroll
        for (int r = 0; r < 4; ++r) {
            int e = mt * 16 + hi * 4 + r;
            qpb[mt][r] = __shfl(qpacc, e);
            w2c[mt][r] = __shfl(w2row, e);
        }

    // q pieces for frag build: qv2[ks][j] = q[ks*32 + hi*8 + j]
    float qv2[2][8];
#pragma unroll
    for (int ks = 0; ks < 2; ++ks)
#pragma unroll
        for (int j = 0; j < 8; ++j)
            qv2[ks][j] = q_l[wv * 64 + ks * 32 + hi * 8 + j];

    // A-frags: qw'[e = mt*16+lo][dd = ks*32 + hi*8 + j], bf16
    short8 af[4][2];
#pragma unroll
    for (int mt = 0; mt < 4; ++mt) {
        const float* wr = w1 + (mt * 16 + lo) * 192;
#pragma unroll
        for (int ks = 0; ks < 2; ++ks) {
            int dd0 = ks * 32 + hi * 8;
            float4 a0 = *(const float4*)(wr + 128 + dd0);
            float4 a1 = *(const float4*)(wr + 128 + dd0 + 4);
            float4 k0 = *(const float4*)(wr + 64 + dd0);
            float4 k1 = *(const float4*)(wr + 64 + dd0 + 4);
            union { u16 u[8]; short8 s; } cv;
            cv.u[0] = f2b(__builtin_fmaf(qv2[ks][0], a0.x, k0.x));
            cv.u[1] = f2b(__builtin_fmaf(qv2[ks][1], a0.y, k0.y));
            cv.u[2] = f2b(__builtin_fmaf(qv2[ks][2], a0.z, k0.z));
            cv.u[3] = f2b(__builtin_fmaf(qv2[ks][3], a0.w, k0.w));
            cv.u[4] = f2b(__builtin_fmaf(qv2[ks][4], a1.x, k1.x));
            cv.u[5] = f2b(__builtin_fmaf(qv2[ks][5], a1.y, k1.y));
            cv.u[6] = f2b(__builtin_fmaf(qv2[ks][6], a1.z, k1.z));
            cv.u[7] = f2b(__builtin_fmaf(qv2[ks][7], a1.w, k1.w));
            af[mt][ks] = cv.s;
        }
    }

    float l_run = 0.f;
    float oa0 = 0.f, oa1 = 0.f, oa2 = 0.f, oa3 = 0.f;
    const u16*   kbase = kb + bh * 65536;
    const float* vbase = vf + bh * 65536;
    const floatx4 z = (floatx4){0.f, 0.f, 0.f, 0.f};

    // prologue: load B-frags for j0 = 0
    short8 bf[2][2];
#pragma unroll
    for (int t = 0; t < 2; ++t)
#pragma unroll
        for (int ks = 0; ks < 2; ++ks) {
            uint4 kv = *(const uint4*)(kbase + (t * 16 + lo) * 64 + ks * 32 + hi * 8);
            bf[t][ks] = *(short8*)&kv;
        }

    for (int j0 = 0; j0 < 1024; j0 += 32) {
        // prefetch next iter's B-frags (latency overlapped with body below)
        int jn = (j0 + 32) & 1023;                 // last prefetch wraps, unused
        short8 bfn[2][2];
#pragma unroll
        for (int t = 0; t < 2; ++t)
#pragma unroll
            for (int ks = 0; ks < 2; ++ks) {
                uint4 kv = *(const uint4*)(kbase + (jn + t * 16 + lo) * 64 + ks * 32 + hi * 8);
                bfn[t][ks] = *(short8*)&kv;
            }

        floatx4 acc[4][2];
#pragma unroll
        for (int mt = 0; mt < 4; ++mt)
#pragma unroll
            for (int t = 0; t < 2; ++t)
                acc[mt][t] = __builtin_amdgcn_mfma_f32_16x16x32_bf16(af[mt][0], bf[t][0], z, 0, 0, 0);
#pragma unroll
        for (int mt = 0; mt < 4; ++mt)
#pragma unroll
            for (int t = 0; t < 2; ++t)
                acc[mt][t] = __builtin_amdgcn_mfma_f32_16x16x32_bf16(af[mt][1], bf[t][1], acc[mt][t], 0, 0, 0);

        // score[j]: sigmoid-gelu (HW exp2) + pair-merged rcp
        float s0 = 0.f, s1 = 0.f;
#pragma unroll
        for (int mt = 0; mt < 4; ++mt)
#pragma unroll
            for (int r = 0; r < 4; ++r) {
                float x0 = acc[mt][0][r] + qpb[mt][r];
                float x1 = acc[mt][1][r] + qpb[mt][r];
                float e0 = __builtin_amdgcn_exp2f(x0 * -2.45546696f);
                float e1 = __builtin_amdgcn_exp2f(x1 * -2.45546696f);
                float a0 = 1.0f + e0;
                float a1 = 1.0f + e1;
                float rc = __builtin_amdgcn_rcpf(a0 * a1);
                s0 = __builtin_fmaf(x0 * w2c[mt][r], rc * a1, s0);
                s1 = __builtin_fmaf(x1 * w2c[mt][r], rc * a0, s1);
            }
        s0 += __shfl_xor(s0, 16); s0 += __shfl_xor(s0, 32);   // s[j=lo]
        s1 += __shfl_xor(s1, 16); s1 += __shfl_xor(s1, 32);   // s[j=16+lo]

        // fixed-shift softmax numerator (scores bounded |s|<~110, safe)
        float p0 = __builtin_amdgcn_exp2f(s0 - 16.0f);
        float p1 = __builtin_amdgcn_exp2f(s1 - 16.0f);
        l_run += p0 + p1;                          // per-lane partial (over lo)

        // PV: p[j=lane&15] lives in p0/p1 -> v_readlane broadcast, SGPR fma
        const float* vrow = vbase + j0 * 64 + lane;
#pragma unroll
        for (int j = 0; j < 16; j += 4) {
            float pa0 = rdlane(p0, j + 0), pb0 = rdlane(p1, j + 0);
            float pa1 = rdlane(p0, j + 1), pb1 = rdlane(p1, j + 1);
            float pa2 = rdlane(p0, j + 2), pb2 = rdlane(p1, j + 2);
            float pa3 = rdlane(p0, j + 3), pb3 = rdlane(p1, j + 3);
            oa0 = __builtin_fmaf(pa0, vrow[(j + 0) * 64], oa0);
            oa1 = __builtin_fmaf(pa1, vrow[(j + 1) * 64], oa1);
            oa2 = __builtin_fmaf(pa2, vrow[(j + 2) * 64], oa2);
            oa3 = __builtin_fmaf(pa3, vrow[(j + 3) * 64], oa3);
            oa0 = __builtin_fmaf(pb0, vrow[(j + 16) * 64], oa0);
            oa1 = __builtin_fmaf(pb1, vrow[(j + 17) * 64], oa1);
            oa2 = __builtin_fmaf(pb2, vrow[(j + 18) * 64], oa2);
            oa3 = __builtin_fmaf(pb3, vrow[(j + 19) * 64], oa3);
        }

        // rotate pipeline
#pragma unroll
        for (int t = 0; t < 2; ++t)
#pragma unroll
            for (int ks = 0; ks < 2; ++ks)
                bf[t][ks] = bfn[t][ks];
    }

    float l = l_run;
    l += __shfl_xor(l, 1); l += __shfl_xor(l, 2);
    l += __shfl_xor(l, 4); l += __shfl_xor(l, 8);
    float outv = (oa0 + oa1 + oa2 + oa3) * __builtin_amdgcn_rcpf(l);
    int b = bh >> 3, h = bh & 7;
    ao[(b * 1024 + qi) * 512 + h * 64 + lane] = outv;   // (B,C,D) fp32
}

// ---------------------------------------------------------------------------
extern "C" void kernel_launch(void* const* d_in, const int* in_sizes, int n_in,
                              void* d_out, int out_size, void* d_ws, size_t ws_size,
                              hipStream_t stream)
{
    (void)in_sizes; (void)n_in; (void)out_size; (void)ws_size;
    const float* x  = (const float*)d_in[0];
    const float* Wq = (const float*)d_in[1];
    const float* bq = (const float*)d_in[2];
    const float* Wk = (const float*)d_in[3];
    const float* bk = (const float*)d_in[4];
    const float* Wv = (const float*)d_in[5];
    const float* bv = (const float*)d_in[6];
    const float* w1 = (const float*)d_in[7];
    const float* b1 = (const float*)d_in[8];
    const float* w2 = (const float*)d_in[9];
    // d_in[10] = b2: scalar shift of all scores -> softmax-invariant -> unused
    const float* Wo = (const float*)d_in[11];
    const float* bo = (const float*)d_in[12];

    char* ws = (char*)d_ws;
    float* q_ws = (float*)(ws);               // 4 MB fp32 (b,h,c,d)
    u16*   k_ws = (u16*)(ws + (4u << 20));    // 2 MB bf16 (b,h,c,d)
    float* v_ws = (float*)(ws + (6u << 20));  // 4 MB fp32 (b,h,c,d)
    float* a_ws = (float*)(ws + (10u << 20)); // 4 MB fp32 (b,c,D)

    dim3 blk(256);
    hipLaunchKernelGGL(gemm_qkv, dim3(32, 24), blk, 0, stream,
                       x, Wq, Wk, Wv, bq, bk, bv, q_ws, k_ws, v_ws);
    hipLaunchKernelGGL(attn6, dim3(4096), blk, 0, stream, q_ws, k_ws, v_ws, w1, b1, w2, a_ws);
    hipLaunchKernelGGL(gemm_out, dim3(32, 8), blk, 0, stream, a_ws, Wo, bo, (float*)d_out);
}